// Round 2
// baseline (462.811 us; speedup 1.0000x reference)
//
#include <hip/hip_runtime.h>

typedef __bf16 bf16_t;
typedef __bf16 bf16x4 __attribute__((ext_vector_type(4)));
typedef __bf16 bf16x8 __attribute__((ext_vector_type(8)));
typedef float floatx4 __attribute__((ext_vector_type(4)));

#define G_GRAPHS 64
#define N_NODES 2000
#define N_EDGES 64000
#define BATCH 10000
#define TED_ 512
#define NOISE_ 128
#define PACDIM_ 6400
#define D0_ 1024
#define D1_ 512
#define MROWS 1000   // BATCH / PAC
#define S0 8          // split-K for layer 0
#define S1 8          // split-K for layer 1

#define GRAPH_BLKS 64
#define PACK_BLKS 5000
#define W0T_BLKS 6400   // (6400/32)*(1024/32)
#define W1T_BLKS 512    // (1024/32)*(512/32)

// ---------------- async global->LDS helper (16B per lane) ----------------
__device__ __forceinline__ void glds16(const void* g, void* l) {
    __builtin_amdgcn_global_load_lds(
        (__attribute__((address_space(1))) void*)(g),
        (__attribute__((address_space(3))) void*)(l), 16, 0, 0);
}

// ============ kernel A: mega prep ============
// blocks [0,64):           whole-graph GCN (deg+msg+finish) + gnoise GEMV, LDS-only
// blocks [64,5064):        pack input_ -> A bf16
// blocks [5064,11464):     transpose W0 -> W0t bf16
// blocks [11464,11976):    transpose W1 -> W1t bf16
__global__ __launch_bounds__(256) void prep_kernel(
    const int* __restrict__ edge_index, const float* __restrict__ graphs_x,
    const float* __restrict__ gcn_w, const float* __restrict__ gcn_b,
    const float* __restrict__ gme_w, const float* __restrict__ gme_b,
    float* __restrict__ gnoise,
    const float* __restrict__ in, bf16_t* __restrict__ A,
    const float* __restrict__ W0, bf16_t* __restrict__ W0t,
    const float* __restrict__ W1, bf16_t* __restrict__ W1t)
{
    __shared__ __align__(16) char smraw[25088];
    const int b = blockIdx.x, tid = threadIdx.x;

    if (b < GRAPH_BLKS) {
        float* xs = (float*)smraw;        // [2000]
        float* dg = xs + N_NODES;         // [2000] deg -> dinv
        float* oh = dg + N_NODES;         // [2000] msg acc -> gcn out
        float* part = oh + N_NODES;       // [2][128]
        const int g = b;
        const float* xg = graphs_x + (size_t)g * N_NODES;
        for (int n = tid; n < N_NODES; n += 256) {
            xs[n] = xg[n]; dg[n] = 0.f; oh[n] = 0.f;
        }
        __syncthreads();
        const int* src = edge_index + (size_t)g * 2 * N_EDGES;
        const int* dst = src + N_EDGES;
        for (int e = tid; e < N_EDGES; e += 256) atomicAdd(&dg[dst[e]], 1.0f);
        __syncthreads();
        for (int n = tid; n < N_NODES; n += 256) dg[n] = rsqrtf(dg[n] + 1.0f);
        __syncthreads();
        for (int e = tid; e < N_EDGES; e += 256) {
            int ss = src[e], dd = dst[e];
            atomicAdd(&oh[dd], xs[ss] * dg[ss] * dg[dd]);
        }
        __syncthreads();
        const float w = gcn_w[0], bb = gcn_b[0];
        for (int n = tid; n < N_NODES; n += 256)
            oh[n] = w * (oh[n] + xs[n] * dg[n] * dg[n]) + bb;   // self-loop term
        __syncthreads();
        // gnoise[g, j] = sum_n oh[n] * gme_w[n,j]  (+ gme_b folded here)
        const int j = tid & 127, ch = tid >> 7;
        const float* wp = gme_w + (size_t)(ch * 1000) * 128 + j;
        const float* op = oh + ch * 1000;
        float acc = 0.f;
        #pragma unroll 4
        for (int n = 0; n < 1000; n++)
            acc += op[n] * wp[(size_t)n * 128];
        part[ch * 128 + j] = acc;
        __syncthreads();
        if (tid < 128)
            gnoise[(size_t)g * 128 + tid] = part[tid] + part[128 + tid] + gme_b[tid];
        return;
    }
    if (b < GRAPH_BLKS + PACK_BLKS) {
        int idx = (b - GRAPH_BLKS) * 256 + tid;   // over BATCH*512/4
        float4 v = ((const float4*)in)[idx];
        int bb = idx >> 7;
        int c = (idx & 127) << 2;
        int r = bb / 10, slot = bb - r * 10;
        bf16x4 o = { (bf16_t)v.x, (bf16_t)v.y, (bf16_t)v.z, (bf16_t)v.w };
        *(bf16x4*)(A + (size_t)r * PACDIM_ + slot * 640 + c) = o;
        return;
    }
    float (*t)[33] = (float(*)[33])smraw;
    const float* W; bf16_t* Wt; int Rr, Cc, c0, r0;
    if (b < GRAPH_BLKS + PACK_BLKS + W0T_BLKS) {
        int tile = b - (GRAPH_BLKS + PACK_BLKS);  // 200x32 tiles
        W = W0; Wt = W0t; Rr = PACDIM_; Cc = D0_;
        c0 = (tile & 31) << 5; r0 = (tile >> 5) << 5;
    } else {
        int tile = b - (GRAPH_BLKS + PACK_BLKS + W0T_BLKS);  // 32x16 tiles
        W = W1; Wt = W1t; Rr = D0_; Cc = D1_;
        c0 = (tile & 15) << 5; r0 = (tile >> 4) << 5;
    }
    int tx = tid & 31, ty = tid >> 5;
    for (int yy = ty; yy < 32; yy += 8)
        t[yy][tx] = W[(size_t)(r0 + yy) * Cc + c0 + tx];
    __syncthreads();
    for (int yy = ty; yy < 32; yy += 8)
        Wt[(size_t)(c0 + yy) * Rr + r0 + tx] = (bf16_t)t[tx][yy];
}

// ------- kernel D: meta MLP + noise cols -> A (gnoise already has gme_b) -------
__global__ __launch_bounds__(256) void meta_kernel(
    const float* __restrict__ chain, const float* __restrict__ metadata,
    const int* __restrict__ graph_ids,
    const float* __restrict__ meta_w, const float* __restrict__ meta_b,
    const float* __restrict__ gme_w,
    const float* __restrict__ gnoise, bf16_t* __restrict__ A)
{
    int wid = (blockIdx.x * 256 + threadIdx.x) >> 6;
    int lane = threadIdx.x & 63;
    if (wid >= BATCH) return;
    const int b = wid;
    float me = 0.f;
    if (lane < 32) {
        me = meta_b[lane] + chain[b] * meta_w[lane];
        for (int i = 1; i < 16; i++)
            me += metadata[(size_t)b * 15 + (i - 1)] * meta_w[(size_t)i * 32 + lane];
        me = me > 0.f ? me : 0.f;
    }
    const int gid = graph_ids[b];
    const float* gp = gnoise + (size_t)gid * 128;
    const int j1 = lane, j2 = lane + 64;
    float n1 = gp[j1];
    float n2 = gp[j2];
    for (int k = 0; k < 32; k++) {
        float mk = __shfl(me, k, 64);
        const float* wrow = gme_w + (size_t)(N_NODES + k) * 128;
        n1 += mk * wrow[j1];
        n2 += mk * wrow[j2];
    }
    int r = b / 10, slot = b - r * 10;
    bf16_t* dp = A + (size_t)r * PACDIM_ + slot * 640 + TED_;
    dp[j1] = (bf16_t)n1;
    dp[j2] = (bf16_t)n2;
}

// -------- kernel 5: split-K GEMM, double-buffered, XCD-swizzled flat grid --------
// BM=BN=128, BK=32, 256 thr = 4 waves
// flat id: z = id & (2^zbits-1) -> same-z blocks land on same XCD (id%8 dispatch),
//          x = (id>>zbits) & (2^xbits-1), y = id >> (zbits+xbits)
__global__ __launch_bounds__(256) void gemm_bt_splitk_kernel(
    const bf16_t* __restrict__ A,   // [M,K] row-major
    const bf16_t* __restrict__ Bt,  // [N,K] row-major
    float* __restrict__ P,          // [S, Mp, N] fp32 partials
    int M, int N, int K, int KS, int zbits, int xbits, int Mp)
{
    __shared__ __align__(16) bf16_t As[2][128 * 32];
    __shared__ __align__(16) bf16_t Bs[2][128 * 32];
    const int tid = threadIdx.x;
    const int wave = tid >> 6;
    const int lane = tid & 63;
    const int id = blockIdx.x;
    const int z = id & ((1 << zbits) - 1);
    const int xt = (id >> zbits) & ((1 << xbits) - 1);
    const int yt = id >> (zbits + xbits);
    const int mBase = yt * 128;
    const int nBase = xt * 128;
    const int wm = (wave & 1) * 64;
    const int wn = (wave >> 1) * 64;

    floatx4 acc[4][4] = {};

    const int rA0 = tid >> 2, k80 = (tid & 3) * 8;
    int gm0 = mBase + rA0;      if (gm0 > M - 1) gm0 = M - 1;
    int gm1 = mBase + 64 + rA0; if (gm1 > M - 1) gm1 = M - 1;
    const bf16_t* aP0 = A + (size_t)gm0 * K + k80;
    const bf16_t* aP1 = A + (size_t)gm1 * K + k80;
    const bf16_t* bP0 = Bt + (size_t)(nBase + rA0) * K + k80;
    const bf16_t* bP1 = Bt + (size_t)(nBase + 64 + rA0) * K + k80;

    const int kq = (lane >> 4) * 8;
    const int mr = lane & 15;
    int aOff[4], bOff[4];
    for (int i = 0; i < 4; i++) aOff[i] = (wm + i * 16 + mr) * 32 + kq;
    for (int j = 0; j < 4; j++) bOff[j] = (wn + j * 16 + mr) * 32 + kq;

    const int nIter = KS >> 5;
    const int kc = z * KS;
    {   // prologue: stage tile 0 into buffer 0
        char* lA = (char*)(&As[0][0]) + wave * 1024;
        char* lB = (char*)(&Bs[0][0]) + wave * 1024;
        glds16(aP0 + kc, lA);
        glds16(aP1 + kc, lA + 4096);
        glds16(bP0 + kc, lB);
        glds16(bP1 + kc, lB + 4096);
    }
    __syncthreads();
    for (int t = 0; t < nIter; ++t) {
        const int cur = t & 1;
        if (t + 1 < nIter) {     // issue next-tile loads BEFORE compute
            const int kn = kc + (t + 1) * 32;
            char* lA = (char*)(&As[cur ^ 1][0]) + wave * 1024;
            char* lB = (char*)(&Bs[cur ^ 1][0]) + wave * 1024;
            glds16(aP0 + kn, lA);
            glds16(aP1 + kn, lA + 4096);
            glds16(bP0 + kn, lB);
            glds16(bP1 + kn, lB + 4096);
        }
        const bf16_t* aB = &As[cur][0];
        const bf16_t* bB = &Bs[cur][0];
        bf16x8 af[4], bfr[4];
        for (int i = 0; i < 4; i++) af[i] = *(const bf16x8*)(aB + aOff[i]);
        for (int j = 0; j < 4; j++) bfr[j] = *(const bf16x8*)(bB + bOff[j]);
        for (int i = 0; i < 4; i++)
            for (int j = 0; j < 4; j++)
                acc[i][j] = __builtin_amdgcn_mfma_f32_16x16x32_bf16(
                    af[i], bfr[j], acc[i][j], 0, 0, 0);
        __syncthreads();
    }

    float* Pz = P + (size_t)z * Mp * N;
    const int rq = (lane >> 4) * 4;
    const int cn = lane & 15;
    for (int j = 0; j < 4; j++) {
        int col = nBase + wn + j * 16 + cn;
        for (int i = 0; i < 4; i++)
            for (int r = 0; r < 4; r++) {
                int rowm = mBase + wm + i * 16 + rq + r;
                Pz[(size_t)rowm * N + col] = acc[i][j][r];
            }
    }
}

// -------- kernel 5b: reduce split-K partials + bias + leaky -> bf16 --------
__global__ __launch_bounds__(256) void reduce_bias_leaky_kernel(
    const float* __restrict__ P, const float* __restrict__ bias,
    bf16_t* __restrict__ C, int M, int N, int Mp, int S)
{
    int idx = blockIdx.x * 256 + threadIdx.x;
    int total = M * (N >> 2);
    if (idx >= total) return;
    int nv = N >> 2;
    int r = idx / nv, c4 = (idx - r * nv) << 2;
    size_t off = (size_t)r * N + c4;
    size_t stride = (size_t)Mp * N;
    float4 v = *(const float4*)(P + off);
    for (int s = 1; s < S; s++) {
        float4 u = *(const float4*)(P + s * stride + off);
        v.x += u.x; v.y += u.y; v.z += u.z; v.w += u.w;
    }
    const float4 bv = *(const float4*)(bias + c4);
    v.x += bv.x; v.y += bv.y; v.z += bv.z; v.w += bv.w;
    v.x = v.x > 0.f ? v.x : 0.2f * v.x;
    v.y = v.y > 0.f ? v.y : 0.2f * v.y;
    v.z = v.z > 0.f ? v.z : 0.2f * v.z;
    v.w = v.w > 0.f ? v.w : 0.2f * v.w;
    bf16x4 o = { (bf16_t)v.x, (bf16_t)v.y, (bf16_t)v.z, (bf16_t)v.w };
    *(bf16x4*)(C + off) = o;
}

// ---- kernel 6: fused reduce(P1) + bias + leaky + dot(w2) + b2 -> out[r] ----
__global__ __launch_bounds__(256) void final_fused_kernel(
    const float* __restrict__ P, const float* __restrict__ b1,
    const float* __restrict__ w2, const float* __restrict__ b2,
    float* __restrict__ out, int Mp, int S)
{
    int wid = (blockIdx.x * 256 + threadIdx.x) >> 6;
    int lane = threadIdx.x & 63;
    if (wid >= MROWS) return;
    size_t stride = (size_t)Mp * D1_;
    const float* base = P + (size_t)wid * D1_;
    float s = 0.f;
    for (int i = 0; i < 8; i++) {
        int c = i * 64 + lane;
        float v = base[c];
        for (int z = 1; z < S; z++) v += base[(size_t)z * stride + c];
        v += b1[c];
        v = v > 0.f ? v : 0.2f * v;
        s += v * w2[c];
    }
    for (int off = 32; off; off >>= 1) s += __shfl_down(s, off, 64);
    if (lane == 0) out[wid] = s + b2[0];
}

// ---------------------------- launcher ----------------------------
extern "C" void kernel_launch(void* const* d_in, const int* in_sizes, int n_in,
                              void* d_out, int out_size, void* d_ws, size_t ws_size,
                              hipStream_t stream)
{
    const float* input_    = (const float*)d_in[0];
    const float* graphs_x  = (const float*)d_in[1];
    const int*   edge_idx  = (const int*)  d_in[2];
    const int*   graph_ids = (const int*)  d_in[3];
    const float* chain     = (const float*)d_in[4];
    const float* metadata  = (const float*)d_in[5];
    const float* gcn_w     = (const float*)d_in[6];
    const float* gcn_b     = (const float*)d_in[7];
    const float* meta_w    = (const float*)d_in[8];
    const float* meta_b    = (const float*)d_in[9];
    const float* gme_w     = (const float*)d_in[10];
    const float* gme_b     = (const float*)d_in[11];
    const float* seq_w0    = (const float*)d_in[12];
    const float* seq_b0    = (const float*)d_in[13];
    const float* seq_w1    = (const float*)d_in[14];
    const float* seq_b1    = (const float*)d_in[15];
    const float* seq_w2    = (const float*)d_in[16];
    const float* seq_b2    = (const float*)d_in[17];
    float* out = (float*)d_out;

    char* ws = (char*)d_ws;
    float*  gnoise = (float*)(ws + 0);               // 64*128*4    =     32768
    bf16_t* Abuf   = (bf16_t*)(ws + 32768);          // 1000*6400*2 =  12800000
    bf16_t* W0t    = (bf16_t*)(ws + 12832768);       // 6400*1024*2 =  13107200
    bf16_t* W1t    = (bf16_t*)(ws + 25939968);       // 1024*512*2  =   1048576
    bf16_t* H1     = (bf16_t*)(ws + 26988544);       // 1000*1024*2 =   2048000
    float*  P      = (float*)(ws + 29036544);        // 8*1024*1024*4 = 33554432
    // total ~62.6 MB

    // A: graph GCN+GEMV | pack input | transpose W0 | transpose W1 (independent)
    prep_kernel<<<GRAPH_BLKS + PACK_BLKS + W0T_BLKS + W1T_BLKS, 256, 0, stream>>>(
        edge_idx, graphs_x, gcn_w, gcn_b, gme_w, gme_b, gnoise,
        input_, Abuf, seq_w0, W0t, seq_w1, W1t);
    // B: meta MLP + noise columns into A
    meta_kernel<<<2500, 256, 0, stream>>>(
        chain, metadata, graph_ids, meta_w, meta_b, gme_w, gnoise, Abuf);

    // layer 0: M=1000 N=1024 K=6400, split-K=8 (KS=800), 8x8x8=512 blocks flat
    gemm_bt_splitk_kernel<<<512, 256, 0, stream>>>(
        Abuf, W0t, P, MROWS, D0_, PACDIM_, PACDIM_ / S0, 3, 3, 1024);
    reduce_bias_leaky_kernel<<<(MROWS * D0_ / 4 + 255) / 256, 256, 0, stream>>>(
        P, seq_b0, H1, MROWS, D0_, 1024, S0);

    // layer 1: M=1000 N=512 K=1024, split-K=8 (KS=128), 4x8x8=256 blocks flat
    gemm_bt_splitk_kernel<<<256, 256, 0, stream>>>(
        H1, W1t, P, MROWS, D1_, D0_, D0_ / S1, 3, 2, 1024);
    final_fused_kernel<<<(MROWS * 64 + 255) / 256, 256, 0, stream>>>(
        P, seq_b1, seq_w2, seq_b2, out, 1024, S1);
}

// Round 3
// 265.575 us; speedup vs baseline: 1.7427x; 1.7427x over previous
//
#include <hip/hip_runtime.h>

typedef __bf16 bf16_t;
typedef __bf16 bf16x4 __attribute__((ext_vector_type(4)));
typedef __bf16 bf16x8 __attribute__((ext_vector_type(8)));
typedef float floatx4 __attribute__((ext_vector_type(4)));

#define G_GRAPHS 64
#define N_NODES 2000
#define N_EDGES 64000
#define BATCH 10000
#define TED_ 512
#define NOISE_ 128
#define PACDIM_ 6400
#define D0_ 1024
#define D1_ 512
#define MROWS 1000   // BATCH / PAC
#define ESPLIT 8
#define EPB (N_EDGES / ESPLIT)   // 8000 edges per block
#define S0 8          // split-K for layer 0
#define S1 8          // split-K for layer 1

// ---------------- async global->LDS helper (16B per lane) ----------------
__device__ __forceinline__ void glds16(const void* g, void* l) {
    __builtin_amdgcn_global_load_lds(
        (__attribute__((address_space(1))) void*)(g),
        (__attribute__((address_space(3))) void*)(l), 16, 0, 0);
}

// ------------- kernel A: prep (deg partials | pack input | transpose W0/W1) -------------
// blocks [0,512): degree histogram partials (no global atomics)
// blocks [512,5512): pack input_ -> A bf16
// blocks [5512,11912): transpose W0 -> W0t bf16
// blocks [11912,12424): transpose W1 -> W1t bf16
__global__ __launch_bounds__(256) void prep_kernel(
    const int* __restrict__ edge_index, float* __restrict__ degs_part,
    const float* __restrict__ in, bf16_t* __restrict__ A,
    const float* __restrict__ W0, bf16_t* __restrict__ W0t,
    const float* __restrict__ W1, bf16_t* __restrict__ W1t)
{
    __shared__ float h[N_NODES];
    __shared__ float t[32][33];
    const int b = blockIdx.x, tid = threadIdx.x;
    if (b < 512) {
        const int s = b & 7, g = b >> 3;
        for (int n = tid; n < N_NODES; n += 256) h[n] = 0.f;
        __syncthreads();
        const int* dst = edge_index + (size_t)g * 2 * N_EDGES + N_EDGES + s * EPB;
        for (int e = tid; e < EPB; e += 256) atomicAdd(&h[dst[e]], 1.0f);
        __syncthreads();
        float* dp = degs_part + ((size_t)g * ESPLIT + s) * N_NODES;
        for (int n = tid; n < N_NODES; n += 256) dp[n] = h[n];
        return;
    }
    if (b < 5512) {
        int idx = (b - 512) * 256 + tid;          // over BATCH*512/4
        float4 v = ((const float4*)in)[idx];
        int bb = idx >> 7;
        int c = (idx & 127) << 2;
        int r = bb / 10, slot = bb - r * 10;
        bf16x4 o = { (bf16_t)v.x, (bf16_t)v.y, (bf16_t)v.z, (bf16_t)v.w };
        *(bf16x4*)(A + (size_t)r * PACDIM_ + slot * 640 + c) = o;
        return;
    }
    const float* W; bf16_t* Wt; int Rr, Cc, c0, r0;
    if (b < 11912) {
        int tile = b - 5512;                      // 200x32 tiles
        W = W0; Wt = W0t; Rr = PACDIM_; Cc = D0_;
        c0 = (tile & 31) << 5; r0 = (tile >> 5) << 5;
    } else {
        int tile = b - 11912;                     // 32x16 tiles
        W = W1; Wt = W1t; Rr = D0_; Cc = D1_;
        c0 = (tile & 15) << 5; r0 = (tile >> 4) << 5;
    }
    int tx = tid & 31, ty = tid >> 5;
    for (int yy = ty; yy < 32; yy += 8)
        t[yy][tx] = W[(size_t)(r0 + yy) * Cc + c0 + tx];
    __syncthreads();
    for (int yy = ty; yy < 32; yy += 8)
        Wt[(size_t)(c0 + yy) * Rr + r0 + tx] = (bf16_t)t[tx][yy];
}

// ---------- kernel B: message pass partials (no global atomics) ----------
__global__ __launch_bounds__(512) void msg_kernel(
    const float* __restrict__ graphs_x, const int* __restrict__ edge_index,
    const float* __restrict__ degs_part, float* __restrict__ outs_part)
{
    __shared__ float xs[N_NODES];
    __shared__ float dv[N_NODES];
    __shared__ float oh[N_NODES];
    const int g = blockIdx.y, s = blockIdx.x, tid = threadIdx.x;
    const float* xg = graphs_x + (size_t)g * N_NODES;
    const float* dgp = degs_part + (size_t)g * ESPLIT * N_NODES;
    for (int n = tid; n < N_NODES; n += 512) {
        xs[n] = xg[n];
        float d = 1.0f;                            // +1 self-loop
        for (int p = 0; p < ESPLIT; p++) d += dgp[(size_t)p * N_NODES + n];
        dv[n] = rsqrtf(d);
        oh[n] = 0.f;
    }
    __syncthreads();
    const int* src = edge_index + (size_t)g * 2 * N_EDGES + s * EPB;
    const int* dst = src + N_EDGES;
    for (int e = tid; e < EPB; e += 512) {
        int ss = src[e], dd = dst[e];
        atomicAdd(&oh[dd], xs[ss] * dv[ss] * dv[dd]);
    }
    __syncthreads();
    float* op = outs_part + ((size_t)g * ESPLIT + s) * N_NODES;
    for (int n = tid; n < N_NODES; n += 512) op[n] = oh[n];
}

// ---------- kernel C: finish gcn + gnoise partial GEMV (plain writes) ----------
__global__ __launch_bounds__(512) void gnoise_kernel(
    const float* __restrict__ graphs_x, const float* __restrict__ degs_part,
    const float* __restrict__ outs_part,
    const float* __restrict__ gcn_w, const float* __restrict__ gcn_b,
    const float* __restrict__ gme_w, float* __restrict__ gnoise_p)
{
    __shared__ float of[500];
    __shared__ float part[4][128];
    const int s = blockIdx.x, g = blockIdx.y, tid = threadIdx.x;
    const int nBase = s * 500;
    const float w = gcn_w[0], bb = gcn_b[0];
    const float* dgp = degs_part + (size_t)g * ESPLIT * N_NODES;
    const float* otp = outs_part + (size_t)g * ESPLIT * N_NODES;
    for (int n = tid; n < 500; n += 512) {
        int gn = nBase + n;
        float d = 1.0f, o = 0.f;
        for (int p = 0; p < ESPLIT; p++) {
            d += dgp[(size_t)p * N_NODES + gn];
            o += otp[(size_t)p * N_NODES + gn];
        }
        of[n] = w * (o + graphs_x[(size_t)g * N_NODES + gn] / d) + bb;
    }
    __syncthreads();
    const int j = tid & 127, ch = tid >> 7;
    float acc = 0.f;
    const int n0 = ch * 125;
    for (int n = n0; n < n0 + 125; n++)
        acc += of[n] * gme_w[(size_t)(nBase + n) * 128 + j];
    part[ch][j] = acc;
    __syncthreads();
    if (tid < 128)
        gnoise_p[((size_t)g * 4 + s) * 128 + tid] =
            part[0][tid] + part[1][tid] + part[2][tid] + part[3][tid];
}

// ------- kernel D: meta MLP + noise cols -> A (sums 4 gnoise partials inline) -------
__global__ __launch_bounds__(256) void meta_kernel(
    const float* __restrict__ chain, const float* __restrict__ metadata,
    const int* __restrict__ graph_ids,
    const float* __restrict__ meta_w, const float* __restrict__ meta_b,
    const float* __restrict__ gme_w, const float* __restrict__ gme_b,
    const float* __restrict__ gnoise_p, bf16_t* __restrict__ A)
{
    int wid = (blockIdx.x * 256 + threadIdx.x) >> 6;
    int lane = threadIdx.x & 63;
    if (wid >= BATCH) return;
    const int b = wid;
    float me = 0.f;
    if (lane < 32) {
        me = meta_b[lane] + chain[b] * meta_w[lane];
        for (int i = 1; i < 16; i++)
            me += metadata[(size_t)b * 15 + (i - 1)] * meta_w[(size_t)i * 32 + lane];
        me = me > 0.f ? me : 0.f;
    }
    const int gid = graph_ids[b];
    const float* gp = gnoise_p + (size_t)gid * 4 * 128;
    const int j1 = lane, j2 = lane + 64;
    float n1 = gme_b[j1] + gp[j1] + gp[128 + j1] + gp[256 + j1] + gp[384 + j1];
    float n2 = gme_b[j2] + gp[j2] + gp[128 + j2] + gp[256 + j2] + gp[384 + j2];
    for (int k = 0; k < 32; k++) {
        float mk = __shfl(me, k, 64);
        const float* wrow = gme_w + (size_t)(N_NODES + k) * 128;
        n1 += mk * wrow[j1];
        n2 += mk * wrow[j2];
    }
    int r = b / 10, slot = b - r * 10;
    bf16_t* dp = A + (size_t)r * PACDIM_ + slot * 640 + TED_;
    dp[j1] = (bf16_t)n1;
    dp[j2] = (bf16_t)n2;
}

// -------- kernel 5: split-K GEMM, double-buffered, XCD-swizzled flat grid --------
// BM=BN=128, BK=32, 256 thr = 4 waves
// flat id: z = id & (2^zbits-1) -> same-z blocks land on same XCD (id%8 dispatch),
//          x = (id>>zbits) & (2^xbits-1), y = id >> (zbits+xbits)
__global__ __launch_bounds__(256) void gemm_bt_splitk_kernel(
    const bf16_t* __restrict__ A,   // [M,K] row-major
    const bf16_t* __restrict__ Bt,  // [N,K] row-major
    float* __restrict__ P,          // [S, Mp, N] fp32 partials
    int M, int N, int K, int KS, int zbits, int xbits, int Mp)
{
    __shared__ __align__(16) bf16_t As[2][128 * 32];
    __shared__ __align__(16) bf16_t Bs[2][128 * 32];
    const int tid = threadIdx.x;
    const int wave = tid >> 6;
    const int lane = tid & 63;
    const int id = blockIdx.x;
    const int z = id & ((1 << zbits) - 1);
    const int xt = (id >> zbits) & ((1 << xbits) - 1);
    const int yt = id >> (zbits + xbits);
    const int mBase = yt * 128;
    const int nBase = xt * 128;
    const int wm = (wave & 1) * 64;
    const int wn = (wave >> 1) * 64;

    floatx4 acc[4][4] = {};

    const int rA0 = tid >> 2, k80 = (tid & 3) * 8;
    int gm0 = mBase + rA0;      if (gm0 > M - 1) gm0 = M - 1;
    int gm1 = mBase + 64 + rA0; if (gm1 > M - 1) gm1 = M - 1;
    const bf16_t* aP0 = A + (size_t)gm0 * K + k80;
    const bf16_t* aP1 = A + (size_t)gm1 * K + k80;
    const bf16_t* bP0 = Bt + (size_t)(nBase + rA0) * K + k80;
    const bf16_t* bP1 = Bt + (size_t)(nBase + 64 + rA0) * K + k80;

    const int kq = (lane >> 4) * 8;
    const int mr = lane & 15;
    int aOff[4], bOff[4];
    for (int i = 0; i < 4; i++) aOff[i] = (wm + i * 16 + mr) * 32 + kq;
    for (int j = 0; j < 4; j++) bOff[j] = (wn + j * 16 + mr) * 32 + kq;

    const int nIter = KS >> 5;
    const int kc = z * KS;
    {   // prologue: stage tile 0 into buffer 0
        char* lA = (char*)(&As[0][0]) + wave * 1024;
        char* lB = (char*)(&Bs[0][0]) + wave * 1024;
        glds16(aP0 + kc, lA);
        glds16(aP1 + kc, lA + 4096);
        glds16(bP0 + kc, lB);
        glds16(bP1 + kc, lB + 4096);
    }
    __syncthreads();
    for (int t = 0; t < nIter; ++t) {
        const int cur = t & 1;
        if (t + 1 < nIter) {     // issue next-tile loads BEFORE compute
            const int kn = kc + (t + 1) * 32;
            char* lA = (char*)(&As[cur ^ 1][0]) + wave * 1024;
            char* lB = (char*)(&Bs[cur ^ 1][0]) + wave * 1024;
            glds16(aP0 + kn, lA);
            glds16(aP1 + kn, lA + 4096);
            glds16(bP0 + kn, lB);
            glds16(bP1 + kn, lB + 4096);
        }
        const bf16_t* aB = &As[cur][0];
        const bf16_t* bB = &Bs[cur][0];
        bf16x8 af[4], bfr[4];
        for (int i = 0; i < 4; i++) af[i] = *(const bf16x8*)(aB + aOff[i]);
        for (int j = 0; j < 4; j++) bfr[j] = *(const bf16x8*)(bB + bOff[j]);
        for (int i = 0; i < 4; i++)
            for (int j = 0; j < 4; j++)
                acc[i][j] = __builtin_amdgcn_mfma_f32_16x16x32_bf16(
                    af[i], bfr[j], acc[i][j], 0, 0, 0);
        __syncthreads();
    }

    float* Pz = P + (size_t)z * Mp * N;
    const int rq = (lane >> 4) * 4;
    const int cn = lane & 15;
    for (int j = 0; j < 4; j++) {
        int col = nBase + wn + j * 16 + cn;
        for (int i = 0; i < 4; i++)
            for (int r = 0; r < 4; r++) {
                int rowm = mBase + wm + i * 16 + rq + r;
                Pz[(size_t)rowm * N + col] = acc[i][j][r];
            }
    }
}

// -------- kernel 5b: reduce split-K partials + bias + leaky -> bf16 --------
__global__ __launch_bounds__(256) void reduce_bias_leaky_kernel(
    const float* __restrict__ P, const float* __restrict__ bias,
    bf16_t* __restrict__ C, int M, int N, int Mp, int S)
{
    int idx = blockIdx.x * 256 + threadIdx.x;
    int total = M * (N >> 2);
    if (idx >= total) return;
    int nv = N >> 2;
    int r = idx / nv, c4 = (idx - r * nv) << 2;
    size_t off = (size_t)r * N + c4;
    size_t stride = (size_t)Mp * N;
    float4 v = *(const float4*)(P + off);
    for (int s = 1; s < S; s++) {
        float4 u = *(const float4*)(P + s * stride + off);
        v.x += u.x; v.y += u.y; v.z += u.z; v.w += u.w;
    }
    const float4 bv = *(const float4*)(bias + c4);
    v.x += bv.x; v.y += bv.y; v.z += bv.z; v.w += bv.w;
    v.x = v.x > 0.f ? v.x : 0.2f * v.x;
    v.y = v.y > 0.f ? v.y : 0.2f * v.y;
    v.z = v.z > 0.f ? v.z : 0.2f * v.z;
    v.w = v.w > 0.f ? v.w : 0.2f * v.w;
    bf16x4 o = { (bf16_t)v.x, (bf16_t)v.y, (bf16_t)v.z, (bf16_t)v.w };
    *(bf16x4*)(C + off) = o;
}

// ---- kernel 6: fused reduce(P1) + bias + leaky + dot(w2) + b2 -> out[r] ----
__global__ __launch_bounds__(256) void final_fused_kernel(
    const float* __restrict__ P, const float* __restrict__ b1,
    const float* __restrict__ w2, const float* __restrict__ b2,
    float* __restrict__ out, int Mp, int S)
{
    int wid = (blockIdx.x * 256 + threadIdx.x) >> 6;
    int lane = threadIdx.x & 63;
    if (wid >= MROWS) return;
    size_t stride = (size_t)Mp * D1_;
    const float* base = P + (size_t)wid * D1_;
    float s = 0.f;
    for (int i = 0; i < 8; i++) {
        int c = i * 64 + lane;
        float v = base[c];
        for (int z = 1; z < S; z++) v += base[(size_t)z * stride + c];
        v += b1[c];
        v = v > 0.f ? v : 0.2f * v;
        s += v * w2[c];
    }
    for (int off = 32; off; off >>= 1) s += __shfl_down(s, off, 64);
    if (lane == 0) out[wid] = s + b2[0];
}

// ---------------------------- launcher ----------------------------
extern "C" void kernel_launch(void* const* d_in, const int* in_sizes, int n_in,
                              void* d_out, int out_size, void* d_ws, size_t ws_size,
                              hipStream_t stream)
{
    const float* input_    = (const float*)d_in[0];
    const float* graphs_x  = (const float*)d_in[1];
    const int*   edge_idx  = (const int*)  d_in[2];
    const int*   graph_ids = (const int*)  d_in[3];
    const float* chain     = (const float*)d_in[4];
    const float* metadata  = (const float*)d_in[5];
    const float* gcn_w     = (const float*)d_in[6];
    const float* gcn_b     = (const float*)d_in[7];
    const float* meta_w    = (const float*)d_in[8];
    const float* meta_b    = (const float*)d_in[9];
    const float* gme_w     = (const float*)d_in[10];
    const float* gme_b     = (const float*)d_in[11];
    const float* seq_w0    = (const float*)d_in[12];
    const float* seq_b0    = (const float*)d_in[13];
    const float* seq_w1    = (const float*)d_in[14];
    const float* seq_b1    = (const float*)d_in[15];
    const float* seq_w2    = (const float*)d_in[16];
    const float* seq_b2    = (const float*)d_in[17];
    float* out = (float*)d_out;

    char* ws = (char*)d_ws;
    // workspace layout (no pre-zeroing needed anywhere: all plain writes)
    float*  degs_part = (float*)(ws + 0);            // 64*8*2000*4 =  4,096,000
    float*  outs_part = (float*)(ws + 4096000);      // 64*8*2000*4 =  4,096,000
    float*  gnoise_p  = (float*)(ws + 8192000);      // 64*4*128*4  =    131,072
    bf16_t* Abuf      = (bf16_t*)(ws + 8323072);     // 1000*6400*2 = 12,800,000
    bf16_t* W0t       = (bf16_t*)(ws + 21123072);    // 6400*1024*2 = 13,107,200
    bf16_t* W1t       = (bf16_t*)(ws + 34230272);    // 1024*512*2  =  1,048,576
    bf16_t* H1        = (bf16_t*)(ws + 35278848);    // 1000*1024*2 =  2,048,000
    float*  P         = (float*)(ws + 37326848);     // 8*1024*1024*4 = 33,554,432
    // total ~70.9 MB

    // A: deg partials | pack input | transpose W0 | transpose W1 (all independent)
    prep_kernel<<<12424, 256, 0, stream>>>(
        edge_idx, degs_part, input_, Abuf, seq_w0, W0t, seq_w1, W1t);
    // B: message pass partials (reads deg partials for dinv)
    msg_kernel<<<dim3(ESPLIT, G_GRAPHS), 512, 0, stream>>>(
        graphs_x, edge_idx, degs_part, outs_part);
    // C: finish GCN + gnoise partial GEMV
    gnoise_kernel<<<dim3(4, G_GRAPHS), 512, 0, stream>>>(
        graphs_x, degs_part, outs_part, gcn_w, gcn_b, gme_w, gnoise_p);
    // D: meta MLP + noise columns into A
    meta_kernel<<<2500, 256, 0, stream>>>(
        chain, metadata, graph_ids, meta_w, meta_b, gme_w, gme_b,
        gnoise_p, Abuf);

    // layer 0: M=1000 N=1024 K=6400, split-K=8 (KS=800), 8x8x8=512 blocks flat
    gemm_bt_splitk_kernel<<<512, 256, 0, stream>>>(
        Abuf, W0t, P, MROWS, D0_, PACDIM_, PACDIM_ / S0, 3, 3, 1024);
    reduce_bias_leaky_kernel<<<(MROWS * D0_ / 4 + 255) / 256, 256, 0, stream>>>(
        P, seq_b0, H1, MROWS, D0_, 1024, S0);

    // layer 1: M=1000 N=512 K=1024, split-K=8 (KS=128), 4x8x8=256 blocks flat
    gemm_bt_splitk_kernel<<<256, 256, 0, stream>>>(
        H1, W1t, P, MROWS, D1_, D0_, D0_ / S1, 3, 2, 1024);
    final_fused_kernel<<<(MROWS * 64 + 255) / 256, 256, 0, stream>>>(
        P, seq_b1, seq_w2, seq_b2, out, 1024, S1);
}

// Round 4
// 264.246 us; speedup vs baseline: 1.7514x; 1.0050x over previous
//
#include <hip/hip_runtime.h>

typedef __bf16 bf16_t;
typedef __bf16 bf16x4 __attribute__((ext_vector_type(4)));
typedef __bf16 bf16x8 __attribute__((ext_vector_type(8)));
typedef float floatx4 __attribute__((ext_vector_type(4)));

#define G_GRAPHS 64
#define N_NODES 2000
#define N_EDGES 64000
#define BATCH 10000
#define TED_ 512
#define NOISE_ 128
#define PACDIM_ 6400
#define D0_ 1024
#define D1_ 512
#define MROWS 1000   // BATCH / PAC
#define ESPLIT 8
#define EPB (N_EDGES / ESPLIT)      // 8000 edges per deg block
#define MSPLIT 16
#define EPB_MSG (N_EDGES / MSPLIT)  // 4000 edges per msg block
#define S0 8          // split-K for layer 0
#define S1 8          // split-K for layer 1

// ---------------- async global->LDS helper (16B per lane) ----------------
__device__ __forceinline__ void glds16(const void* g, void* l) {
    __builtin_amdgcn_global_load_lds(
        (__attribute__((address_space(1))) void*)(g),
        (__attribute__((address_space(3))) void*)(l), 16, 0, 0);
}

// ------------- kernel A: prep (deg partials | pack input | transpose W0/W1) -------------
// blocks [0,512): degree histogram partials (no global atomics)
// blocks [512,5512): pack input_ -> A bf16
// blocks [5512,11912): transpose W0 -> W0t bf16
// blocks [11912,12424): transpose W1 -> W1t bf16
__global__ __launch_bounds__(256) void prep_kernel(
    const int* __restrict__ edge_index, float* __restrict__ degs_part,
    const float* __restrict__ in, bf16_t* __restrict__ A,
    const float* __restrict__ W0, bf16_t* __restrict__ W0t,
    const float* __restrict__ W1, bf16_t* __restrict__ W1t)
{
    __shared__ float h[N_NODES];
    __shared__ float t[32][33];
    const int b = blockIdx.x, tid = threadIdx.x;
    if (b < 512) {
        const int s = b & 7, g = b >> 3;
        for (int n = tid; n < N_NODES; n += 256) h[n] = 0.f;
        __syncthreads();
        const int4* d4 = (const int4*)(edge_index + (size_t)g * 2 * N_EDGES
                                       + N_EDGES + s * EPB);
        for (int e = tid; e < EPB / 4; e += 256) {
            int4 v = d4[e];
            atomicAdd(&h[v.x], 1.0f); atomicAdd(&h[v.y], 1.0f);
            atomicAdd(&h[v.z], 1.0f); atomicAdd(&h[v.w], 1.0f);
        }
        __syncthreads();
        float* dp = degs_part + ((size_t)g * ESPLIT + s) * N_NODES;
        for (int n = tid; n < N_NODES; n += 256) dp[n] = h[n];
        return;
    }
    if (b < 5512) {
        int idx = (b - 512) * 256 + tid;          // over BATCH*512/4
        float4 v = ((const float4*)in)[idx];
        int bb = idx >> 7;
        int c = (idx & 127) << 2;
        int r = bb / 10, slot = bb - r * 10;
        bf16x4 o = { (bf16_t)v.x, (bf16_t)v.y, (bf16_t)v.z, (bf16_t)v.w };
        *(bf16x4*)(A + (size_t)r * PACDIM_ + slot * 640 + c) = o;
        return;
    }
    const float* W; bf16_t* Wt; int Rr, Cc, c0, r0;
    if (b < 11912) {
        int tile = b - 5512;                      // 200x32 tiles
        W = W0; Wt = W0t; Rr = PACDIM_; Cc = D0_;
        c0 = (tile & 31) << 5; r0 = (tile >> 5) << 5;
    } else {
        int tile = b - 11912;                     // 32x16 tiles
        W = W1; Wt = W1t; Rr = D0_; Cc = D1_;
        c0 = (tile & 15) << 5; r0 = (tile >> 4) << 5;
    }
    int tx = tid & 31, ty = tid >> 5;
    for (int yy = ty; yy < 32; yy += 8)
        t[yy][tx] = W[(size_t)(r0 + yy) * Cc + c0 + tx];
    __syncthreads();
    for (int yy = ty; yy < 32; yy += 8)
        Wt[(size_t)(c0 + yy) * Rr + r0 + tx] = (bf16_t)t[tx][yy];
}

// ---------- kernel B: message pass partials, 16-way edge split ----------
__global__ __launch_bounds__(512) void msg_kernel(
    const float* __restrict__ graphs_x, const int* __restrict__ edge_index,
    const float* __restrict__ degs_part, float* __restrict__ outs_part)
{
    __shared__ float ys[N_NODES];    // x[n]*dinv[n]
    __shared__ float dvl[N_NODES];   // dinv[n]
    __shared__ float oh[N_NODES];
    const int g = blockIdx.y, s = blockIdx.x, tid = threadIdx.x;
    const float* xg = graphs_x + (size_t)g * N_NODES;
    const float* dgp = degs_part + (size_t)g * ESPLIT * N_NODES;
    for (int n = tid; n < N_NODES; n += 512) {
        float d = 1.0f;                            // +1 self-loop
        for (int p = 0; p < ESPLIT; p++) d += dgp[(size_t)p * N_NODES + n];
        float dv = rsqrtf(d);
        dvl[n] = dv;
        ys[n] = xg[n] * dv;
        oh[n] = 0.f;
    }
    __syncthreads();
    const int* src = edge_index + (size_t)g * 2 * N_EDGES + s * EPB_MSG;
    const int2* s2 = (const int2*)src;
    const int2* d2 = (const int2*)(src + N_EDGES);
    for (int e = tid; e < EPB_MSG / 2; e += 512) {
        int2 sv = s2[e], dd = d2[e];
        atomicAdd(&oh[dd.x], ys[sv.x] * dvl[dd.x]);
        atomicAdd(&oh[dd.y], ys[sv.y] * dvl[dd.y]);
    }
    __syncthreads();
    float* op = outs_part + ((size_t)g * MSPLIT + s) * N_NODES;
    for (int n = tid; n < N_NODES; n += 512) op[n] = oh[n];
}

// ---------- kernel C: finish gcn + gnoise partial GEMV (plain writes) ----------
__global__ __launch_bounds__(512) void gnoise_kernel(
    const float* __restrict__ graphs_x, const float* __restrict__ degs_part,
    const float* __restrict__ outs_part,
    const float* __restrict__ gcn_w, const float* __restrict__ gcn_b,
    const float* __restrict__ gme_w, float* __restrict__ gnoise_p)
{
    __shared__ float of[500];
    __shared__ float part[4][128];
    const int s = blockIdx.x, g = blockIdx.y, tid = threadIdx.x;
    const int nBase = s * 500;
    const float w = gcn_w[0], bb = gcn_b[0];
    const float* dgp = degs_part + (size_t)g * ESPLIT * N_NODES;
    const float* otp = outs_part + (size_t)g * MSPLIT * N_NODES;
    for (int n = tid; n < 500; n += 512) {
        int gn = nBase + n;
        float d = 1.0f, o = 0.f;
        for (int p = 0; p < ESPLIT; p++) d += dgp[(size_t)p * N_NODES + gn];
        for (int p = 0; p < MSPLIT; p++) o += otp[(size_t)p * N_NODES + gn];
        of[n] = w * (o + graphs_x[(size_t)g * N_NODES + gn] / d) + bb;
    }
    __syncthreads();
    const int j = tid & 127, ch = tid >> 7;
    float acc = 0.f;
    const int n0 = ch * 125;
    for (int n = n0; n < n0 + 125; n++)
        acc += of[n] * gme_w[(size_t)(nBase + n) * 128 + j];
    part[ch][j] = acc;
    __syncthreads();
    if (tid < 128)
        gnoise_p[((size_t)g * 4 + s) * 128 + tid] =
            part[0][tid] + part[1][tid] + part[2][tid] + part[3][tid];
}

// ------- kernel D: meta MLP + noise cols -> A (sums 4 gnoise partials inline) -------
__global__ __launch_bounds__(256) void meta_kernel(
    const float* __restrict__ chain, const float* __restrict__ metadata,
    const int* __restrict__ graph_ids,
    const float* __restrict__ meta_w, const float* __restrict__ meta_b,
    const float* __restrict__ gme_w, const float* __restrict__ gme_b,
    const float* __restrict__ gnoise_p, bf16_t* __restrict__ A)
{
    int wid = (blockIdx.x * 256 + threadIdx.x) >> 6;
    int lane = threadIdx.x & 63;
    if (wid >= BATCH) return;
    const int b = wid;
    float me = 0.f;
    if (lane < 32) {
        me = meta_b[lane] + chain[b] * meta_w[lane];
        for (int i = 1; i < 16; i++)
            me += metadata[(size_t)b * 15 + (i - 1)] * meta_w[(size_t)i * 32 + lane];
        me = me > 0.f ? me : 0.f;
    }
    const int gid = graph_ids[b];
    const float* gp = gnoise_p + (size_t)gid * 4 * 128;
    const int j1 = lane, j2 = lane + 64;
    float n1 = gme_b[j1] + gp[j1] + gp[128 + j1] + gp[256 + j1] + gp[384 + j1];
    float n2 = gme_b[j2] + gp[j2] + gp[128 + j2] + gp[256 + j2] + gp[384 + j2];
    for (int k = 0; k < 32; k++) {
        float mk = __shfl(me, k, 64);
        const float* wrow = gme_w + (size_t)(N_NODES + k) * 128;
        n1 += mk * wrow[j1];
        n2 += mk * wrow[j2];
    }
    int r = b / 10, slot = b - r * 10;
    bf16_t* dp = A + (size_t)r * PACDIM_ + slot * 640 + TED_;
    dp[j1] = (bf16_t)n1;
    dp[j2] = (bf16_t)n2;
}

// -------- kernel 5: split-K GEMM, double-buffered, XOR-swizzled LDS --------
// BM=BN=128, BK=32, 256 thr = 4 waves
// LDS tile [128][32] bf16: granule g (16B) of row r stored at g^((r>>1)&3)
// -> applied as source-pre-swizzle (linear glds16 dest) + swizzled ds_read.
// Bank slots become 16*(r&1)+4*(g^f): 8 slots, 2 lanes/slot = conflict-free.
__global__ __launch_bounds__(256) void gemm_bt_splitk_kernel(
    const bf16_t* __restrict__ A,   // [M,K] row-major
    const bf16_t* __restrict__ Bt,  // [N,K] row-major
    float* __restrict__ P,          // [S, Mp, N] fp32 partials
    int M, int N, int K, int KS, int zbits, int xbits, int Mp)
{
    __shared__ __align__(16) bf16_t As[2][128 * 32];
    __shared__ __align__(16) bf16_t Bs[2][128 * 32];
    const int tid = threadIdx.x;
    const int wave = tid >> 6;
    const int lane = tid & 63;
    const int id = blockIdx.x;
    const int z = id & ((1 << zbits) - 1);
    const int xt = (id >> zbits) & ((1 << xbits) - 1);
    const int yt = id >> (zbits + xbits);
    const int mBase = yt * 128;
    const int nBase = xt * 128;
    const int wm = (wave & 1) * 64;
    const int wn = (wave >> 1) * 64;

    floatx4 acc[4][4] = {};

    // staging: thread covers row rA0 (within 64-row half), granule g4;
    // source granule swizzled by f4 = (row>>1)&3
    const int rA0 = tid >> 2;
    const int g4 = tid & 3;
    const int f4 = (rA0 >> 1) & 3;
    const int k8 = (g4 ^ f4) * 8;     // element offset within 32-col row
    int gm0 = mBase + rA0;      if (gm0 > M - 1) gm0 = M - 1;
    int gm1 = mBase + 64 + rA0; if (gm1 > M - 1) gm1 = M - 1;
    const bf16_t* aP0 = A + (size_t)gm0 * K + k8;
    const bf16_t* aP1 = A + (size_t)gm1 * K + k8;
    const bf16_t* bP0 = Bt + (size_t)(nBase + rA0) * K + k8;
    const bf16_t* bP1 = Bt + (size_t)(nBase + 64 + rA0) * K + k8;

    // fragment read: logical granule q at row (..+mr) lives at granule q^((mr>>1)&3)
    const int q4 = lane >> 4;
    const int mr = lane & 15;
    const int kq = ((q4 ^ ((mr >> 1) & 3)) * 8);
    int aOff[4], bOff[4];
    for (int i = 0; i < 4; i++) aOff[i] = (wm + i * 16 + mr) * 32 + kq;
    for (int j = 0; j < 4; j++) bOff[j] = (wn + j * 16 + mr) * 32 + kq;

    const int nIter = KS >> 5;
    const int kc = z * KS;
    {   // prologue: stage tile 0 into buffer 0
        char* lA = (char*)(&As[0][0]) + wave * 1024;
        char* lB = (char*)(&Bs[0][0]) + wave * 1024;
        glds16(aP0 + kc, lA);
        glds16(aP1 + kc, lA + 4096);
        glds16(bP0 + kc, lB);
        glds16(bP1 + kc, lB + 4096);
    }
    __syncthreads();
    for (int t = 0; t < nIter; ++t) {
        const int cur = t & 1;
        if (t + 1 < nIter) {     // issue next-tile loads BEFORE compute
            const int kn = kc + (t + 1) * 32;
            char* lA = (char*)(&As[cur ^ 1][0]) + wave * 1024;
            char* lB = (char*)(&Bs[cur ^ 1][0]) + wave * 1024;
            glds16(aP0 + kn, lA);
            glds16(aP1 + kn, lA + 4096);
            glds16(bP0 + kn, lB);
            glds16(bP1 + kn, lB + 4096);
        }
        const bf16_t* aB = &As[cur][0];
        const bf16_t* bB = &Bs[cur][0];
        bf16x8 af[4], bfr[4];
        for (int i = 0; i < 4; i++) af[i] = *(const bf16x8*)(aB + aOff[i]);
        for (int j = 0; j < 4; j++) bfr[j] = *(const bf16x8*)(bB + bOff[j]);
        for (int i = 0; i < 4; i++)
            for (int j = 0; j < 4; j++)
                acc[i][j] = __builtin_amdgcn_mfma_f32_16x16x32_bf16(
                    af[i], bfr[j], acc[i][j], 0, 0, 0);
        __syncthreads();
    }

    float* Pz = P + (size_t)z * Mp * N;
    const int rq = (lane >> 4) * 4;
    const int cn = lane & 15;
    for (int j = 0; j < 4; j++) {
        int col = nBase + wn + j * 16 + cn;
        for (int i = 0; i < 4; i++)
            for (int r = 0; r < 4; r++) {
                int rowm = mBase + wm + i * 16 + rq + r;
                Pz[(size_t)rowm * N + col] = acc[i][j][r];
            }
    }
}

// -------- kernel 5b: reduce split-K partials + bias + leaky -> bf16 --------
__global__ __launch_bounds__(256) void reduce_bias_leaky_kernel(
    const float* __restrict__ P, const float* __restrict__ bias,
    bf16_t* __restrict__ C, int M, int N, int Mp, int S)
{
    int idx = blockIdx.x * 256 + threadIdx.x;
    int total = M * (N >> 2);
    if (idx >= total) return;
    int nv = N >> 2;
    int r = idx / nv, c4 = (idx - r * nv) << 2;
    size_t off = (size_t)r * N + c4;
    size_t stride = (size_t)Mp * N;
    float4 v = *(const float4*)(P + off);
    for (int s = 1; s < S; s++) {
        float4 u = *(const float4*)(P + s * stride + off);
        v.x += u.x; v.y += u.y; v.z += u.z; v.w += u.w;
    }
    const float4 bv = *(const float4*)(bias + c4);
    v.x += bv.x; v.y += bv.y; v.z += bv.z; v.w += bv.w;
    v.x = v.x > 0.f ? v.x : 0.2f * v.x;
    v.y = v.y > 0.f ? v.y : 0.2f * v.y;
    v.z = v.z > 0.f ? v.z : 0.2f * v.z;
    v.w = v.w > 0.f ? v.w : 0.2f * v.w;
    bf16x4 o = { (bf16_t)v.x, (bf16_t)v.y, (bf16_t)v.z, (bf16_t)v.w };
    *(bf16x4*)(C + off) = o;
}

// ---- kernel 6: fused reduce(P1) + bias + leaky + dot(w2) + b2 -> out[r] ----
__global__ __launch_bounds__(256) void final_fused_kernel(
    const float* __restrict__ P, const float* __restrict__ b1,
    const float* __restrict__ w2, const float* __restrict__ b2,
    float* __restrict__ out, int Mp, int S)
{
    int wid = (blockIdx.x * 256 + threadIdx.x) >> 6;
    int lane = threadIdx.x & 63;
    if (wid >= MROWS) return;
    size_t stride = (size_t)Mp * D1_;
    const float* base = P + (size_t)wid * D1_;
    float s = 0.f;
    for (int i = 0; i < 8; i++) {
        int c = i * 64 + lane;
        float v = base[c];
        for (int z = 1; z < S; z++) v += base[(size_t)z * stride + c];
        v += b1[c];
        v = v > 0.f ? v : 0.2f * v;
        s += v * w2[c];
    }
    for (int off = 32; off; off >>= 1) s += __shfl_down(s, off, 64);
    if (lane == 0) out[wid] = s + b2[0];
}

// ---------------------------- launcher ----------------------------
extern "C" void kernel_launch(void* const* d_in, const int* in_sizes, int n_in,
                              void* d_out, int out_size, void* d_ws, size_t ws_size,
                              hipStream_t stream)
{
    const float* input_    = (const float*)d_in[0];
    const float* graphs_x  = (const float*)d_in[1];
    const int*   edge_idx  = (const int*)  d_in[2];
    const int*   graph_ids = (const int*)  d_in[3];
    const float* chain     = (const float*)d_in[4];
    const float* metadata  = (const float*)d_in[5];
    const float* gcn_w     = (const float*)d_in[6];
    const float* gcn_b     = (const float*)d_in[7];
    const float* meta_w    = (const float*)d_in[8];
    const float* meta_b    = (const float*)d_in[9];
    const float* gme_w     = (const float*)d_in[10];
    const float* gme_b     = (const float*)d_in[11];
    const float* seq_w0    = (const float*)d_in[12];
    const float* seq_b0    = (const float*)d_in[13];
    const float* seq_w1    = (const float*)d_in[14];
    const float* seq_b1    = (const float*)d_in[15];
    const float* seq_w2    = (const float*)d_in[16];
    const float* seq_b2    = (const float*)d_in[17];
    float* out = (float*)d_out;

    char* ws = (char*)d_ws;
    // workspace layout (no pre-zeroing needed anywhere: all plain writes)
    float*  degs_part = (float*)(ws + 0);            // 64*8*2000*4  =  4,096,000
    float*  outs_part = (float*)(ws + 4096000);      // 64*16*2000*4 =  8,192,000
    float*  gnoise_p  = (float*)(ws + 12288000);     // 64*4*128*4   =    131,072
    bf16_t* Abuf      = (bf16_t*)(ws + 12419072);    // 1000*6400*2  = 12,800,000
    bf16_t* W0t       = (bf16_t*)(ws + 25219072);    // 6400*1024*2  = 13,107,200
    bf16_t* W1t       = (bf16_t*)(ws + 38326272);    // 1024*512*2   =  1,048,576
    bf16_t* H1        = (bf16_t*)(ws + 39374848);    // 1000*1024*2  =  2,048,000
    float*  P         = (float*)(ws + 41422848);     // 8*1024*1024*4 = 33,554,432
    // total ~75 MB

    // A: deg partials | pack input | transpose W0 | transpose W1 (all independent)
    prep_kernel<<<12424, 256, 0, stream>>>(
        edge_idx, degs_part, input_, Abuf, seq_w0, W0t, seq_w1, W1t);
    // B: message pass partials (reads deg partials for dinv), 16-way split
    msg_kernel<<<dim3(MSPLIT, G_GRAPHS), 512, 0, stream>>>(
        graphs_x, edge_idx, degs_part, outs_part);
    // C: finish GCN + gnoise partial GEMV
    gnoise_kernel<<<dim3(4, G_GRAPHS), 512, 0, stream>>>(
        graphs_x, degs_part, outs_part, gcn_w, gcn_b, gme_w, gnoise_p);
    // D: meta MLP + noise columns into A
    meta_kernel<<<2500, 256, 0, stream>>>(
        chain, metadata, graph_ids, meta_w, meta_b, gme_w, gme_b,
        gnoise_p, Abuf);

    // layer 0: M=1000 N=1024 K=6400, split-K=8 (KS=800), 8x8x8=512 blocks flat
    gemm_bt_splitk_kernel<<<512, 256, 0, stream>>>(
        Abuf, W0t, P, MROWS, D0_, PACDIM_, PACDIM_ / S0, 3, 3, 1024);
    reduce_bias_leaky_kernel<<<(MROWS * D0_ / 4 + 255) / 256, 256, 0, stream>>>(
        P, seq_b0, H1, MROWS, D0_, 1024, S0);

    // layer 1: M=1000 N=512 K=1024, split-K=8 (KS=128), 4x8x8=256 blocks flat
    gemm_bt_splitk_kernel<<<256, 256, 0, stream>>>(
        H1, W1t, P, MROWS, D1_, D0_, D0_ / S1, 3, 2, 1024);
    final_fused_kernel<<<(MROWS * 64 + 255) / 256, 256, 0, stream>>>(
        P, seq_b1, seq_w2, seq_b2, out, 1024, S1);
}